// Round 25
// baseline (580.382 us; speedup 1.0000x reference)
//
#include <hip/hip_runtime.h>
#include <hip/hip_cooperative_groups.h>

namespace cg = cooperative_groups;

// ---------------------------------------------------------------------------
// InterpretableFusion v25 = v24 (best: 425us) + ONE change: the packed-G
// b-fragment loads are NON-TEMPORAL. Each wave streams 256KB of G per tile
// through the 32KB vector L1 (100% miss, zero reuse within the CU); if L1
// miss-tracking slots cap per-wave memory parallelism, the 256-load b-chain
// is the unexplained 4x of the 53us/tile cost. nt depollutes L1 for this
// unreusable stream. Pre-committed read: dur<400 => theory confirmed;
// dur>480 => nt broke G's L2 residency, revert; ~425 => null, v24 final.
//
//   scores[n,m] = ( x.(G_m l) + x.v_m + l.u_m + c_m )/sqrt(D)
//   y = x Gt_m^T via MFMA (packed-G b-fragments, X tile staged once),
//   s = (y+u).l, softmax -> weights; fused inline per tile.
// Structure: ONE cooperative kernel, ONE grid.sync (d_ws scratch path);
// dynamic atomic tile queue, pre-sync first-tile stage, rotated next-tile
// stage co-issued with the inline fuse.
// ---------------------------------------------------------------------------

typedef __bf16 bf16x8 __attribute__((ext_vector_type(8)));
typedef __bf16 bf16x4 __attribute__((ext_vector_type(4)));
typedef float  f32x4  __attribute__((ext_vector_type(4)));

#define NTOK 50000
#define DDIM 512
#define NMOD 4
#define BN   32
#define NBLK ((NTOK + BN - 1) / BN)        // 1563
#define WOFF ((size_t)NTOK * DDIM)         // weights region (float offset)
#define GFLOATS 524288                     // packed G: 2MB = 524288 floats
#define TAIL_T 1525                        // fallback: tiles >= this defer fuse
#define SCALE 0.044194173824159216f        // 1/sqrt(512)

// X-tile swizzle: row stride 1024B; XOR byte bits 4-6 with row&7 (guide §6 G4)
#define SWZ(r, b) ((((r) * 1024) + (b)) ^ (((r) & 7) << 4))

__global__ __launch_bounds__(512, 2) void mono_kernel(
    const float* __restrict__ gnn, const float* __restrict__ lat,
    const float* __restrict__ Wq, const float* __restrict__ bq,
    const float* __restrict__ Wk, const float* __restrict__ bk,
    float* __restrict__ out, float* __restrict__ sc, int defer)
{
    __shared__ __align__(16) char smem[35392];  // 32K tile + s_part dbuf + wlds
    const int tid = threadIdx.x;
    const int bid = blockIdx.x;
    const int ngrid = gridDim.x;
    cg::grid_group gg = cg::this_grid();

    float* uP = sc + GFLOATS;          // u[m][d']  (4*512)
    float* vP = uP + 2048;             // v[m][d]
    float* cP = vP + 2048;             // c[m]
    float* fP = cP + 4;                // 32 bias-nonzero flags
    int*   qP = (int*)(fP + 32);       // dynamic tile queue counter

    __bf16* tile  = (__bf16*)smem;             // 32 KiB: X tile (phase 2)
    // stage a 32x512 X tile -> swizzled bf16 LDS (nt loads)
    auto stage = [&](int t) {
        const int r0 = t * BN;
        const int vr = (NTOK - r0 < BN) ? (NTOK - r0) : BN;
        const float* src = gnn + (size_t)r0 * DDIM;
        #pragma unroll
        for (int i = 0; i < 8; ++i) {
            int f4 = i * 512 + tid, r = f4 >> 7, c4 = f4 & 127;
            f32x4 v = (r < vr)
                ? __builtin_nontemporal_load(
                      (const f32x4*)(src + (size_t)r * DDIM + c4 * 4))
                : (f32x4){0.f, 0.f, 0.f, 0.f};
            bf16x4 o;
            o[0] = (__bf16)v[0]; o[1] = (__bf16)v[1];
            o[2] = (__bf16)v[2]; o[3] = (__bf16)v[3];
            *(bf16x4*)((char*)tile + SWZ(r, c4 * 8)) = o;
        }
    };

    // ===== phase 1: Gt[m][e][d] = sum_r Wk[m][r][e]*Wq[r][d], PACKED store ===
    {
        if (bid == 0 && tid == 0) *qP = ngrid;   // queue init (fenced by sync)
        float* ldsA = (float*)smem;            // [r][64 e-cols of Wk_m]
        float* ldsB = (float*)(smem + 16384);  // [r][32 d-cols of Wq]
        for (int gb = bid; gb < 512; gb += ngrid) {
            const int m = gb >> 7, ib = gb & 127, eblk = ib >> 4, dpb = ib & 15;
            const int el = tid >> 3, c8 = tid & 7;
            f32x4 ac = {0.f, 0.f, 0.f, 0.f};
            for (int r0 = 0; r0 < DDIM; r0 += 64) {
                __syncthreads();
                #pragma unroll
                for (int it = 0; it < 2; ++it) {
                    int idx = it * 512 + tid, r = idx >> 4, c4 = idx & 15;
                    *(f32x4*)&ldsA[r * 64 + c4 * 4] =
                        *(const f32x4*)&Wk[((size_t)m * DDIM + r0 + r) * DDIM + eblk * 64 + c4 * 4];
                }
                {
                    int r = tid >> 3, c4 = tid & 7;
                    *(f32x4*)&ldsB[r * 32 + c4 * 4] =
                        *(const f32x4*)&Wq[(size_t)(r0 + r) * DDIM + dpb * 32 + c4 * 4];
                }
                __syncthreads();
                for (int r = 0; r < 64; ++r) {
                    float wk = ldsA[r * 64 + el];
                    ac += wk * *(const f32x4*)&ldsB[r * 32 + c8 * 4];
                }
            }
            // packed store: element (e,d): kk=d>>5, g=(d>>3)&3, eta=e>>4,
            // lane = g*16+(e&15); 16B-unit = ((m*16+kk)*32+eta)*64+lane
            __bf16* Gw = (__bf16*)sc;
            const int eta = eblk * 4 + (el >> 4);
            const int lam = (c8 >> 1) * 16 + (el & 15);
            size_t abf = ((((size_t)m * 16 + dpb) * 32 + eta) * 64 + lam) * 8
                         + (c8 & 1) * 4;
            bf16x4 o;
            o[0] = (__bf16)ac[0]; o[1] = (__bf16)ac[1];
            o[2] = (__bf16)ac[2]; o[3] = (__bf16)ac[3];
            *(bf16x4*)(Gw + abf) = o;
        }

        if (bid < 32) {                        // u, v, c + bias flags
            __syncthreads();                   // own block's LDS reads done
            float* up = (float*)smem;          // [4][64]
            float* vp = (float*)smem + 256;    // [4][64]
            const int m2 = bid >> 3, dc = bid & 7;
            if (tid < 256) {
                const int dl2 = tid & 63, eg = tid >> 6;
                const int d = dc * 64 + dl2;
                float us = 0.f, vs = 0.f;
                #pragma unroll 4
                for (int e = eg * 128; e < eg * 128 + 128; ++e) {
                    us += Wk[((size_t)m2 * DDIM + e) * DDIM + d] * bq[e];
                    vs += Wq[(size_t)e * DDIM + d] * bk[m2 * DDIM + e];
                }
                up[eg * 64 + dl2] = us; vp[eg * 64 + dl2] = vs;
            }
            __syncthreads();
            if (tid < 64) {
                const int d = dc * 64 + tid;
                float uu = up[tid] + up[64+tid] + up[128+tid] + up[192+tid];
                float vv = vp[tid] + vp[64+tid] + vp[128+tid] + vp[192+tid];
                uP[m2 * DDIM + d] = uu;
                vP[m2 * DDIM + d] = vv;
                float cp = 0.f;
                if (dc == 0) {
                    #pragma unroll
                    for (int i = 0; i < 8; ++i)
                        cp += bq[tid * 8 + i] * bk[m2 * DDIM + tid * 8 + i];
                    #pragma unroll
                    for (int msk = 1; msk < 64; msk <<= 1)
                        cp += __shfl_xor(cp, msk, 64);
                    if (tid == 0) cP[m2] = cp;
                }
                unsigned long long anyb =
                    __ballot((uu != 0.f) || (vv != 0.f) || (cp != 0.f));
                if (tid == 0) fP[bid] = anyb ? 1.f : 0.f;   // always written
            }
        }

        // PRE-SYNC PROLOGUE: first tile (= bid) staged now; reads only gnn
        // (no phase-1 dependency) -> hides inside the grid.sync wait.
        __syncthreads();                       // protect phase-1 LDS reads
        if (bid < NBLK) stage(bid);
    }
    gg.sync();   // packed Gt/u/v/c/flags/queue visible device-wide (ONE sync)

    // ===== phase 2: scores -> softmax -> weights -> INLINE fuse =====
    {
        float* s_part = (float*)(smem + 32768);    // 2 x [8][32] double buffer
        f32x4* wlds   = (f32x4*)(smem + 34816);    // [32] normalized weights
        int*   tlds   = (int*)(smem + 35328);      // next-tile broadcast
        const __bf16* Gp = (const __bf16*)sc;
        const int lane = tid & 63, w = tid >> 6;
        const int g = (lane >> 4) & 3, c = lane & 15;

        bool bias = false;
        for (int i2 = 0; i2 < 32; ++i2) bias |= (fP[i2] != 0.f);
        float cm[4];
        #pragma unroll
        for (int m = 0; m < 4; ++m) cm[m] = cP[m];

        int t = bid;   // first tile is static (staged pre-sync)
        while (t < NBLK) {
            const int row0 = t * BN;
            __syncthreads();   // stage for THIS tile complete

            float sm[4];   // per-row scores, meaningful for tid < BN
            for (int m = 0; m < NMOD; ++m) {
                float p[2][4];
                if (bias) {
                    float v4[4];
                    #pragma unroll
                    for (int j = 0; j < 4; ++j)
                        v4[j] = vP[m * DDIM + w * 64 + j * 16 + c];
                    #pragma unroll
                    for (int rt = 0; rt < 2; ++rt)
                        #pragma unroll
                        for (int reg = 0; reg < 4; ++reg) {
                            int r = rt * 16 + g * 4 + reg;
                            float tacc = 0.f;
                            #pragma unroll
                            for (int j = 0; j < 4; ++j) {
                                int col = w * 64 + j * 16 + c;
                                float xv = (float)*(const __bf16*)((const char*)tile +
                                                                   SWZ(r, col * 2));
                                tacc += xv * v4[j];
                            }
                            p[rt][reg] = tacc;
                        }
                } else {
                    #pragma unroll
                    for (int rt = 0; rt < 2; ++rt)
                        #pragma unroll
                        for (int reg = 0; reg < 4; ++reg)
                            p[rt][reg] = 0.f;
                }

                const __bf16* gm = Gp + (size_t)m * 262144;   // 512KB per m
                #pragma unroll
                for (int jh = 0; jh < 2; ++jh) {
                    // PREFETCH lv (16 regs, nt): HBM latency hides under the
                    // MFMA k-loop below.
                    float lv[2][2][4];
                    #pragma unroll
                    for (int jj = 0; jj < 2; ++jj) {
                        const int e = w * 64 + (jh * 2 + jj) * 16 + c;
                        #pragma unroll
                        for (int rt = 0; rt < 2; ++rt)
                            #pragma unroll
                            for (int reg = 0; reg < 4; ++reg) {
                                int row = row0 + rt * 16 + g * 4 + reg;
                                lv[jj][rt][reg] = (row < NTOK)
                                    ? __builtin_nontemporal_load(
                                          lat + ((size_t)row * NMOD + m) * DDIM + e)
                                    : 0.f;
                            }
                    }

                    f32x4 kacc[2][2];
                    #pragma unroll
                    for (int rt = 0; rt < 2; ++rt) {
                        kacc[rt][0] = (f32x4){0.f, 0.f, 0.f, 0.f};
                        kacc[rt][1] = (f32x4){0.f, 0.f, 0.f, 0.f};
                    }
                    // packed b-loads: one contiguous 1KB wave read per fragment,
                    // NON-TEMPORAL (zero reuse within the CU; depollute L1)
                    const __bf16* gpk = gm + (w * 4 + jh * 2) * 512 + lane * 8;
                    #pragma unroll 4
                    for (int kk = 0; kk < 16; ++kk) {
                        bf16x8 b0 = __builtin_nontemporal_load(
                                        (const bf16x8*)(gpk + kk * 16384));
                        bf16x8 b1 = __builtin_nontemporal_load(
                                        (const bf16x8*)(gpk + kk * 16384 + 512));
                        bf16x8 a[2];
                        const int kb = kk * 64 + g * 16;
                        a[0] = *(const bf16x8*)((const char*)tile + SWZ(c, kb));
                        a[1] = *(const bf16x8*)((const char*)tile + SWZ(16 + c, kb));
                        kacc[0][0] = __builtin_amdgcn_mfma_f32_16x16x32_bf16(
                            a[0], b0, kacc[0][0], 0, 0, 0);
                        kacc[1][0] = __builtin_amdgcn_mfma_f32_16x16x32_bf16(
                            a[1], b0, kacc[1][0], 0, 0, 0);
                        kacc[0][1] = __builtin_amdgcn_mfma_f32_16x16x32_bf16(
                            a[0], b1, kacc[0][1], 0, 0, 0);
                        kacc[1][1] = __builtin_amdgcn_mfma_f32_16x16x32_bf16(
                            a[1], b1, kacc[1][1], 0, 0, 0);
                    }

                    // dot with prefetched lv
                    #pragma unroll
                    for (int jj = 0; jj < 2; ++jj) {
                        const int e = w * 64 + (jh * 2 + jj) * 16 + c;
                        float uj = bias ? uP[m * DDIM + e] : 0.f;
                        #pragma unroll
                        for (int rt = 0; rt < 2; ++rt)
                            #pragma unroll
                            for (int reg = 0; reg < 4; ++reg)
                                p[rt][reg] += lv[jj][rt][reg] * (kacc[rt][jj][reg] + uj);
                    }
                    __builtin_amdgcn_sched_barrier(0);
                }

                // reduce over 16 c-lanes, then across 8 waves via LDS (dbuf)
                #pragma unroll
                for (int msk = 1; msk < 16; msk <<= 1)
                    #pragma unroll
                    for (int rt = 0; rt < 2; ++rt)
                        #pragma unroll
                        for (int reg = 0; reg < 4; ++reg)
                            p[rt][reg] += __shfl_xor(p[rt][reg], msk, 64);
                float* sp = s_part + (m & 1) * 256;
                if (c == 0) {
                    #pragma unroll
                    for (int rt = 0; rt < 2; ++rt)
                        #pragma unroll
                        for (int reg = 0; reg < 4; ++reg)
                            sp[w * 32 + rt * 16 + g * 4 + reg] = p[rt][reg];
                }
                __syncthreads();                 // s_part[m&1] complete
                if (tid < BN) {
                    float s = 0.f;
                    #pragma unroll
                    for (int ww = 0; ww < 8; ++ww) s += sp[ww * 32 + tid];
                    sm[m] = s + cm[m];
                }
                // no second barrier: next m writes the OTHER s_part buffer
            }
            // after the m=3 barrier, `tile` is dead (all a-reads complete)

            // acquire next tile id (tid 0) alongside the softmax work
            if (tid == 0) *tlds = atomicAdd(qP, 1);
            if (tid < BN) {
                float e0 = __expf(sm[0] * SCALE), e1 = __expf(sm[1] * SCALE),
                      e2 = __expf(sm[2] * SCALE), e3 = __expf(sm[3] * SCALE);
                float iz = 1.f / (e0 + e1 + e2 + e3);
                f32x4 wv = {e0 * iz, e1 * iz, e2 * iz, e3 * iz};
                wlds[tid] = wv;
                if (row0 + tid < NTOK)
                    *(f32x4*)(out + WOFF + (size_t)(row0 + tid) * 4) = wv;
            }
            __syncthreads();                     // wlds + tlds ready

            const int tn = *tlds;
            // ---- ROTATED PREFETCH: stage the NEXT tile now, co-issued with
            //      the fuse below; one drain at the loop-top barrier covers
            //      both (instead of two serial latency exposures).
            if (tn < NBLK) stage(tn);

            // ---- inline fuse: lat re-read L3-served (nt), deep-unrolled so
            //      16 f32x4 loads are in flight (BW-bound, not latency-bound)
            if (!defer || t < TAIL_T) {
                #pragma unroll 4
                for (int i = 0; i < 8; ++i) {
                    int f4 = i * 512 + tid, r = f4 >> 7, c4 = f4 & 127;
                    if (row0 + r < NTOK) {
                        f32x4 w4 = wlds[r];
                        const float* lp = lat + (size_t)(row0 + r) * NMOD * DDIM + c4 * 4;
                        f32x4 l0 = __builtin_nontemporal_load((const f32x4*)(lp));
                        f32x4 l1 = __builtin_nontemporal_load((const f32x4*)(lp + DDIM));
                        f32x4 l2 = __builtin_nontemporal_load((const f32x4*)(lp + 2 * DDIM));
                        f32x4 l3 = __builtin_nontemporal_load((const f32x4*)(lp + 3 * DDIM));
                        f32x4 acc = w4[0] * l0 + w4[1] * l1 + w4[2] * l2 + w4[3] * l3;
                        __builtin_nontemporal_store(acc,
                            (f32x4*)(out + (size_t)(row0 + r) * DDIM + c4 * 4));
                    }
                }
            }
            t = tn;
        }
    }

    // ===== phase 3 (fallback only): fuse the deferred tail tiles =====
    if (defer) {
        gg.sync();   // weights visible; out-tail scratch now dead
        const long t4 = (long)(NTOK - TAIL_T * BN) * 128;   // 153,600
        for (long idx = (long)bid * 512 + tid; idx < t4;
             idx += (long)ngrid * 512) {
            const int row = TAIL_T * BN + (int)(idx >> 7), c4 = (int)(idx & 127);
            f32x4 w4 = *(const f32x4*)(out + WOFF + (size_t)row * 4);
            f32x4 acc = {0.f, 0.f, 0.f, 0.f};
            #pragma unroll
            for (int m = 0; m < NMOD; ++m) {
                f32x4 v = __builtin_nontemporal_load(
                    (const f32x4*)(lat + ((size_t)row * NMOD + m) * DDIM + c4 * 4));
                acc += w4[m] * v;
            }
            __builtin_nontemporal_store(acc,
                (f32x4*)(out + (size_t)row * DDIM + c4 * 4));
        }
    }
}

extern "C" void kernel_launch(void* const* d_in, const int* in_sizes, int n_in,
                              void* d_out, int out_size, void* d_ws, size_t ws_size,
                              hipStream_t stream)
{
    const float* gnn = (const float*)d_in[0];   // [N, D]
    const float* lat = (const float*)d_in[1];   // [N, M, D]
    const float* Wq  = (const float*)d_in[2];   // [D, D]
    const float* bq  = (const float*)d_in[3];   // [D]
    const float* Wk  = (const float*)d_in[4];   // [M, D, D]
    const float* bk  = (const float*)d_in[5];   // [M, D]
    float* out = (float*)d_out;                 // fused [N,D] ++ weights [N,M]

    // scratch: prefer d_ws (single grid.sync); fallback to tail of fused region
    const size_t need = (size_t)(GFLOATS + 2048 + 2048 + 4 + 32 + 64) * 4;
    float* sc;
    int defer;
    if (ws_size >= need) { sc = (float*)d_ws;      defer = 0; }
    else                 { sc = out + 25000000;    defer = 1; }

    int maxb = 0;
    hipError_t oe = hipOccupancyMaxActiveBlocksPerMultiprocessor(
        &maxb, mono_kernel, 512, 0);
    if (oe != hipSuccess || maxb < 1) maxb = 1;
    if (maxb > 4) maxb = 4;
    const int ngrid = 256 * maxb;

    void* args[] = { (void*)&gnn, (void*)&lat, (void*)&Wq, (void*)&bq,
                     (void*)&Wk, (void*)&bk, (void*)&out, (void*)&sc,
                     (void*)&defer };
    hipLaunchCooperativeKernel((const void*)mono_kernel, dim3(ngrid), dim3(512),
                               args, 0, stream);
}

// Round 26
// 422.786 us; speedup vs baseline: 1.3728x; 1.3728x over previous
//
#include <hip/hip_runtime.h>
#include <hip/hip_cooperative_groups.h>

namespace cg = cooperative_groups;

// ---------------------------------------------------------------------------
// InterpretableFusion FINAL (= v22/v24, best measured: 425.4us, absmax 0.0156)
// v25's nt-b-load probe regressed to ~578us (broke G's L2 residency),
// confirming by inversion that the kernel is b-load-latency-bound at L2-hit
// speed — structural for this algorithm at the 128-reg allocation cap
// (BN=64 and deeper pipelining both spill; proven twice each). Reverted.
//
//   scores[n,m] = ( x.(G_m l) + x.v_m + l.u_m + c_m )/sqrt(D)
//   with G_m = Wq^T Wk_m precomputed in bf16, stored in MFMA b-fragment
//   order (contiguous 1KB wave reads, XCD-L2-resident);
//   y = x Gt_m^T via MFMA (X tile staged once per 32-row tile),
//   s = (y+u).l (lat dotted in registers), softmax -> weights;
//   fused = sum_m w_m l_m inline per tile (lat re-read L3-hot).
// Structure: ONE cooperative kernel, ONE grid.sync (d_ws scratch path);
//   dynamic atomic tile queue, pre-sync first-tile stage, rotated next-tile
//   stage co-issued with the inline fuse.
// Trajectory: 1090us (v2) -> 651 (no-spill regs) -> 530 (single sync) ->
//   425 (queue + prologue + rotated prefetch). All single-variable
//   hypotheses (occupancy, spills, G-traffic, I$, nt policies, barriers,
//   tile size) tested; remaining cost is the per-tile G b-load chain.
// ---------------------------------------------------------------------------

typedef __bf16 bf16x8 __attribute__((ext_vector_type(8)));
typedef __bf16 bf16x4 __attribute__((ext_vector_type(4)));
typedef float  f32x4  __attribute__((ext_vector_type(4)));

#define NTOK 50000
#define DDIM 512
#define NMOD 4
#define BN   32
#define NBLK ((NTOK + BN - 1) / BN)        // 1563
#define WOFF ((size_t)NTOK * DDIM)         // weights region (float offset)
#define GFLOATS 524288                     // packed G: 2MB = 524288 floats
#define TAIL_T 1525                        // fallback: tiles >= this defer fuse
#define SCALE 0.044194173824159216f        // 1/sqrt(512)

// X-tile swizzle: row stride 1024B; XOR byte bits 4-6 with row&7 (guide §6 G4)
#define SWZ(r, b) ((((r) * 1024) + (b)) ^ (((r) & 7) << 4))

__global__ __launch_bounds__(512, 2) void mono_kernel(
    const float* __restrict__ gnn, const float* __restrict__ lat,
    const float* __restrict__ Wq, const float* __restrict__ bq,
    const float* __restrict__ Wk, const float* __restrict__ bk,
    float* __restrict__ out, float* __restrict__ sc, int defer)
{
    __shared__ __align__(16) char smem[35392];  // 32K tile + s_part dbuf + wlds
    const int tid = threadIdx.x;
    const int bid = blockIdx.x;
    const int ngrid = gridDim.x;
    cg::grid_group gg = cg::this_grid();

    float* uP = sc + GFLOATS;          // u[m][d']  (4*512)
    float* vP = uP + 2048;             // v[m][d]
    float* cP = vP + 2048;             // c[m]
    float* fP = cP + 4;                // 32 bias-nonzero flags
    int*   qP = (int*)(fP + 32);       // dynamic tile queue counter

    __bf16* tile  = (__bf16*)smem;             // 32 KiB: X tile (phase 2)
    // stage a 32x512 X tile -> swizzled bf16 LDS (nt loads)
    auto stage = [&](int t) {
        const int r0 = t * BN;
        const int vr = (NTOK - r0 < BN) ? (NTOK - r0) : BN;
        const float* src = gnn + (size_t)r0 * DDIM;
        #pragma unroll
        for (int i = 0; i < 8; ++i) {
            int f4 = i * 512 + tid, r = f4 >> 7, c4 = f4 & 127;
            f32x4 v = (r < vr)
                ? __builtin_nontemporal_load(
                      (const f32x4*)(src + (size_t)r * DDIM + c4 * 4))
                : (f32x4){0.f, 0.f, 0.f, 0.f};
            bf16x4 o;
            o[0] = (__bf16)v[0]; o[1] = (__bf16)v[1];
            o[2] = (__bf16)v[2]; o[3] = (__bf16)v[3];
            *(bf16x4*)((char*)tile + SWZ(r, c4 * 8)) = o;
        }
    };

    // ===== phase 1: Gt[m][e][d] = sum_r Wk[m][r][e]*Wq[r][d], PACKED store ===
    {
        if (bid == 0 && tid == 0) *qP = ngrid;   // queue init (fenced by sync)
        float* ldsA = (float*)smem;            // [r][64 e-cols of Wk_m]
        float* ldsB = (float*)(smem + 16384);  // [r][32 d-cols of Wq]
        for (int gb = bid; gb < 512; gb += ngrid) {
            const int m = gb >> 7, ib = gb & 127, eblk = ib >> 4, dpb = ib & 15;
            const int el = tid >> 3, c8 = tid & 7;
            f32x4 ac = {0.f, 0.f, 0.f, 0.f};
            for (int r0 = 0; r0 < DDIM; r0 += 64) {
                __syncthreads();
                #pragma unroll
                for (int it = 0; it < 2; ++it) {
                    int idx = it * 512 + tid, r = idx >> 4, c4 = idx & 15;
                    *(f32x4*)&ldsA[r * 64 + c4 * 4] =
                        *(const f32x4*)&Wk[((size_t)m * DDIM + r0 + r) * DDIM + eblk * 64 + c4 * 4];
                }
                {
                    int r = tid >> 3, c4 = tid & 7;
                    *(f32x4*)&ldsB[r * 32 + c4 * 4] =
                        *(const f32x4*)&Wq[(size_t)(r0 + r) * DDIM + dpb * 32 + c4 * 4];
                }
                __syncthreads();
                for (int r = 0; r < 64; ++r) {
                    float wk = ldsA[r * 64 + el];
                    ac += wk * *(const f32x4*)&ldsB[r * 32 + c8 * 4];
                }
            }
            // packed store: element (e,d): kk=d>>5, g=(d>>3)&3, eta=e>>4,
            // lane = g*16+(e&15); 16B-unit = ((m*16+kk)*32+eta)*64+lane
            __bf16* Gw = (__bf16*)sc;
            const int eta = eblk * 4 + (el >> 4);
            const int lam = (c8 >> 1) * 16 + (el & 15);
            size_t abf = ((((size_t)m * 16 + dpb) * 32 + eta) * 64 + lam) * 8
                         + (c8 & 1) * 4;
            bf16x4 o;
            o[0] = (__bf16)ac[0]; o[1] = (__bf16)ac[1];
            o[2] = (__bf16)ac[2]; o[3] = (__bf16)ac[3];
            *(bf16x4*)(Gw + abf) = o;
        }

        if (bid < 32) {                        // u, v, c + bias flags
            __syncthreads();                   // own block's LDS reads done
            float* up = (float*)smem;          // [4][64]
            float* vp = (float*)smem + 256;    // [4][64]
            const int m2 = bid >> 3, dc = bid & 7;
            if (tid < 256) {
                const int dl2 = tid & 63, eg = tid >> 6;
                const int d = dc * 64 + dl2;
                float us = 0.f, vs = 0.f;
                #pragma unroll 4
                for (int e = eg * 128; e < eg * 128 + 128; ++e) {
                    us += Wk[((size_t)m2 * DDIM + e) * DDIM + d] * bq[e];
                    vs += Wq[(size_t)e * DDIM + d] * bk[m2 * DDIM + e];
                }
                up[eg * 64 + dl2] = us; vp[eg * 64 + dl2] = vs;
            }
            __syncthreads();
            if (tid < 64) {
                const int d = dc * 64 + tid;
                float uu = up[tid] + up[64+tid] + up[128+tid] + up[192+tid];
                float vv = vp[tid] + vp[64+tid] + vp[128+tid] + vp[192+tid];
                uP[m2 * DDIM + d] = uu;
                vP[m2 * DDIM + d] = vv;
                float cp = 0.f;
                if (dc == 0) {
                    #pragma unroll
                    for (int i = 0; i < 8; ++i)
                        cp += bq[tid * 8 + i] * bk[m2 * DDIM + tid * 8 + i];
                    #pragma unroll
                    for (int msk = 1; msk < 64; msk <<= 1)
                        cp += __shfl_xor(cp, msk, 64);
                    if (tid == 0) cP[m2] = cp;
                }
                unsigned long long anyb =
                    __ballot((uu != 0.f) || (vv != 0.f) || (cp != 0.f));
                if (tid == 0) fP[bid] = anyb ? 1.f : 0.f;   // always written
            }
        }

        // PRE-SYNC PROLOGUE: first tile (= bid) staged now; reads only gnn
        // (no phase-1 dependency) -> hides inside the grid.sync wait.
        __syncthreads();                       // protect phase-1 LDS reads
        if (bid < NBLK) stage(bid);
    }
    gg.sync();   // packed Gt/u/v/c/flags/queue visible device-wide (ONE sync)

    // ===== phase 2: scores -> softmax -> weights -> INLINE fuse =====
    {
        float* s_part = (float*)(smem + 32768);    // 2 x [8][32] double buffer
        f32x4* wlds   = (f32x4*)(smem + 34816);    // [32] normalized weights
        int*   tlds   = (int*)(smem + 35328);      // next-tile broadcast
        const __bf16* Gp = (const __bf16*)sc;
        const int lane = tid & 63, w = tid >> 6;
        const int g = (lane >> 4) & 3, c = lane & 15;

        bool bias = false;
        for (int i2 = 0; i2 < 32; ++i2) bias |= (fP[i2] != 0.f);
        float cm[4];
        #pragma unroll
        for (int m = 0; m < 4; ++m) cm[m] = cP[m];

        int t = bid;   // first tile is static (staged pre-sync)
        while (t < NBLK) {
            const int row0 = t * BN;
            __syncthreads();   // stage for THIS tile complete

            float sm[4];   // per-row scores, meaningful for tid < BN
            for (int m = 0; m < NMOD; ++m) {
                float p[2][4];
                if (bias) {
                    float v4[4];
                    #pragma unroll
                    for (int j = 0; j < 4; ++j)
                        v4[j] = vP[m * DDIM + w * 64 + j * 16 + c];
                    #pragma unroll
                    for (int rt = 0; rt < 2; ++rt)
                        #pragma unroll
                        for (int reg = 0; reg < 4; ++reg) {
                            int r = rt * 16 + g * 4 + reg;
                            float tacc = 0.f;
                            #pragma unroll
                            for (int j = 0; j < 4; ++j) {
                                int col = w * 64 + j * 16 + c;
                                float xv = (float)*(const __bf16*)((const char*)tile +
                                                                   SWZ(r, col * 2));
                                tacc += xv * v4[j];
                            }
                            p[rt][reg] = tacc;
                        }
                } else {
                    #pragma unroll
                    for (int rt = 0; rt < 2; ++rt)
                        #pragma unroll
                        for (int reg = 0; reg < 4; ++reg)
                            p[rt][reg] = 0.f;
                }

                const __bf16* gm = Gp + (size_t)m * 262144;   // 512KB per m
                #pragma unroll
                for (int jh = 0; jh < 2; ++jh) {
                    // PREFETCH lv (16 regs, nt): HBM latency hides under the
                    // MFMA k-loop below.
                    float lv[2][2][4];
                    #pragma unroll
                    for (int jj = 0; jj < 2; ++jj) {
                        const int e = w * 64 + (jh * 2 + jj) * 16 + c;
                        #pragma unroll
                        for (int rt = 0; rt < 2; ++rt)
                            #pragma unroll
                            for (int reg = 0; reg < 4; ++reg) {
                                int row = row0 + rt * 16 + g * 4 + reg;
                                lv[jj][rt][reg] = (row < NTOK)
                                    ? __builtin_nontemporal_load(
                                          lat + ((size_t)row * NMOD + m) * DDIM + e)
                                    : 0.f;
                            }
                    }

                    f32x4 kacc[2][2];
                    #pragma unroll
                    for (int rt = 0; rt < 2; ++rt) {
                        kacc[rt][0] = (f32x4){0.f, 0.f, 0.f, 0.f};
                        kacc[rt][1] = (f32x4){0.f, 0.f, 0.f, 0.f};
                    }
                    // packed b-loads: one contiguous 1KB wave read per fragment
                    const __bf16* gpk = gm + (w * 4 + jh * 2) * 512 + lane * 8;
                    #pragma unroll 4
                    for (int kk = 0; kk < 16; ++kk) {
                        bf16x8 b0 = *(const bf16x8*)(gpk + kk * 16384);
                        bf16x8 b1 = *(const bf16x8*)(gpk + kk * 16384 + 512);
                        bf16x8 a[2];
                        const int kb = kk * 64 + g * 16;
                        a[0] = *(const bf16x8*)((const char*)tile + SWZ(c, kb));
                        a[1] = *(const bf16x8*)((const char*)tile + SWZ(16 + c, kb));
                        kacc[0][0] = __builtin_amdgcn_mfma_f32_16x16x32_bf16(
                            a[0], b0, kacc[0][0], 0, 0, 0);
                        kacc[1][0] = __builtin_amdgcn_mfma_f32_16x16x32_bf16(
                            a[1], b0, kacc[1][0], 0, 0, 0);
                        kacc[0][1] = __builtin_amdgcn_mfma_f32_16x16x32_bf16(
                            a[0], b1, kacc[0][1], 0, 0, 0);
                        kacc[1][1] = __builtin_amdgcn_mfma_f32_16x16x32_bf16(
                            a[1], b1, kacc[1][1], 0, 0, 0);
                    }

                    // dot with prefetched lv
                    #pragma unroll
                    for (int jj = 0; jj < 2; ++jj) {
                        const int e = w * 64 + (jh * 2 + jj) * 16 + c;
                        float uj = bias ? uP[m * DDIM + e] : 0.f;
                        #pragma unroll
                        for (int rt = 0; rt < 2; ++rt)
                            #pragma unroll
                            for (int reg = 0; reg < 4; ++reg)
                                p[rt][reg] += lv[jj][rt][reg] * (kacc[rt][jj][reg] + uj);
                    }
                    __builtin_amdgcn_sched_barrier(0);
                }

                // reduce over 16 c-lanes, then across 8 waves via LDS (dbuf)
                #pragma unroll
                for (int msk = 1; msk < 16; msk <<= 1)
                    #pragma unroll
                    for (int rt = 0; rt < 2; ++rt)
                        #pragma unroll
                        for (int reg = 0; reg < 4; ++reg)
                            p[rt][reg] += __shfl_xor(p[rt][reg], msk, 64);
                float* sp = s_part + (m & 1) * 256;
                if (c == 0) {
                    #pragma unroll
                    for (int rt = 0; rt < 2; ++rt)
                        #pragma unroll
                        for (int reg = 0; reg < 4; ++reg)
                            sp[w * 32 + rt * 16 + g * 4 + reg] = p[rt][reg];
                }
                __syncthreads();                 // s_part[m&1] complete
                if (tid < BN) {
                    float s = 0.f;
                    #pragma unroll
                    for (int ww = 0; ww < 8; ++ww) s += sp[ww * 32 + tid];
                    sm[m] = s + cm[m];
                }
                // no second barrier: next m writes the OTHER s_part buffer
            }
            // after the m=3 barrier, `tile` is dead (all a-reads complete)

            // acquire next tile id (tid 0) alongside the softmax work
            if (tid == 0) *tlds = atomicAdd(qP, 1);
            if (tid < BN) {
                float e0 = __expf(sm[0] * SCALE), e1 = __expf(sm[1] * SCALE),
                      e2 = __expf(sm[2] * SCALE), e3 = __expf(sm[3] * SCALE);
                float iz = 1.f / (e0 + e1 + e2 + e3);
                f32x4 wv = {e0 * iz, e1 * iz, e2 * iz, e3 * iz};
                wlds[tid] = wv;
                if (row0 + tid < NTOK)
                    *(f32x4*)(out + WOFF + (size_t)(row0 + tid) * 4) = wv;
            }
            __syncthreads();                     // wlds + tlds ready

            const int tn = *tlds;
            // ---- ROTATED PREFETCH: stage the NEXT tile now, co-issued with
            //      the fuse below; one drain at the loop-top barrier covers
            //      both (instead of two serial latency exposures).
            if (tn < NBLK) stage(tn);

            // ---- inline fuse: lat re-read L3-served (nt), deep-unrolled so
            //      16 f32x4 loads are in flight (BW-bound, not latency-bound)
            if (!defer || t < TAIL_T) {
                #pragma unroll 4
                for (int i = 0; i < 8; ++i) {
                    int f4 = i * 512 + tid, r = f4 >> 7, c4 = f4 & 127;
                    if (row0 + r < NTOK) {
                        f32x4 w4 = wlds[r];
                        const float* lp = lat + (size_t)(row0 + r) * NMOD * DDIM + c4 * 4;
                        f32x4 l0 = __builtin_nontemporal_load((const f32x4*)(lp));
                        f32x4 l1 = __builtin_nontemporal_load((const f32x4*)(lp + DDIM));
                        f32x4 l2 = __builtin_nontemporal_load((const f32x4*)(lp + 2 * DDIM));
                        f32x4 l3 = __builtin_nontemporal_load((const f32x4*)(lp + 3 * DDIM));
                        f32x4 acc = w4[0] * l0 + w4[1] * l1 + w4[2] * l2 + w4[3] * l3;
                        __builtin_nontemporal_store(acc,
                            (f32x4*)(out + (size_t)(row0 + r) * DDIM + c4 * 4));
                    }
                }
            }
            t = tn;
        }
    }

    // ===== phase 3 (fallback only): fuse the deferred tail tiles =====
    if (defer) {
        gg.sync();   // weights visible; out-tail scratch now dead
        const long t4 = (long)(NTOK - TAIL_T * BN) * 128;   // 153,600
        for (long idx = (long)bid * 512 + tid; idx < t4;
             idx += (long)ngrid * 512) {
            const int row = TAIL_T * BN + (int)(idx >> 7), c4 = (int)(idx & 127);
            f32x4 w4 = *(const f32x4*)(out + WOFF + (size_t)row * 4);
            f32x4 acc = {0.f, 0.f, 0.f, 0.f};
            #pragma unroll
            for (int m = 0; m < NMOD; ++m) {
                f32x4 v = __builtin_nontemporal_load(
                    (const f32x4*)(lat + ((size_t)row * NMOD + m) * DDIM + c4 * 4));
                acc += w4[m] * v;
            }
            __builtin_nontemporal_store(acc,
                (f32x4*)(out + (size_t)row * DDIM + c4 * 4));
        }
    }
}

extern "C" void kernel_launch(void* const* d_in, const int* in_sizes, int n_in,
                              void* d_out, int out_size, void* d_ws, size_t ws_size,
                              hipStream_t stream)
{
    const float* gnn = (const float*)d_in[0];   // [N, D]
    const float* lat = (const float*)d_in[1];   // [N, M, D]
    const float* Wq  = (const float*)d_in[2];   // [D, D]
    const float* bq  = (const float*)d_in[3];   // [D]
    const float* Wk  = (const float*)d_in[4];   // [M, D, D]
    const float* bk  = (const float*)d_in[5];   // [M, D]
    float* out = (float*)d_out;                 // fused [N,D] ++ weights [N,M]

    // scratch: prefer d_ws (single grid.sync); fallback to tail of fused region
    const size_t need = (size_t)(GFLOATS + 2048 + 2048 + 4 + 32 + 64) * 4;
    float* sc;
    int defer;
    if (ws_size >= need) { sc = (float*)d_ws;      defer = 0; }
    else                 { sc = out + 25000000;    defer = 1; }

    int maxb = 0;
    hipError_t oe = hipOccupancyMaxActiveBlocksPerMultiprocessor(
        &maxb, mono_kernel, 512, 0);
    if (oe != hipSuccess || maxb < 1) maxb = 1;
    if (maxb > 4) maxb = 4;
    const int ngrid = 256 * maxb;

    void* args[] = { (void*)&gnn, (void*)&lat, (void*)&Wq, (void*)&bq,
                     (void*)&Wk, (void*)&bk, (void*)&out, (void*)&sc,
                     (void*)&defer };
    hipLaunchCooperativeKernel((const void*)mono_kernel, dim3(ngrid), dim3(512),
                               args, 0, stream);
}